// Round 6
// baseline (55.910 us; speedup 1.0000x reference)
//
#include <hip/hip_runtime.h>
#include <stdint.h>

#define N_GATES    16384
#define NUM_IN     256
#define NUM_OUT    256
#define MID_LAYERS 15
#define LAYERS_TOT 16              // layer0 + 15 mid (out layer handled separately)
#define W          4096
#define BLOCK      1024
#define WG_COLS    16              // bit-columns per workgroup (uint16 words)
#define NUM_WG     (W / WG_COLS)   // 256 -> one WG per CU
#define QPT        4               // quads (of 4 gates) per thread

// ---------------------------------------------------------------------------
// Prep: greedy two-choice operand orientation, register-resident counters.
// NAND/NOR are commutative -> each gate may swap (a,b). The two operand reads
// of a gate land in two distinct wave instructions; greedily orienting each
// gate toward the less-loaded LDS bank drives per-instruction max bank load
// from ~4.8 (random) toward ~2, and 2-way is conflict-free (m136).
//
// The greedy chain runs entirely in VGPRs: each of the two per-instruction
// bank-load tables is 32 packed 4-bit counters in 2x uint64 (dynamic shifts,
// fully static storage -> no scratch). Counters saturate at 15: saturation
// only degrades optimization quality, never correctness (any orientation is
// a valid commutative swap). ~35 VALU/gate x 64 gates ~= 2.2K cyc/slot.
//
// Grid: 256 blocks = (layer 0..15, wave-group 0..15), 64 threads; threads
// 0..15 each own one (q,k) instruction slot.
// Descriptor: a*2 | nor<<15 | (b*2)<<16 (pre-scaled u16 byte addresses).
// ---------------------------------------------------------------------------
__device__ __forceinline__ uint32_t nib_get(uint64_t lo, uint64_t hi, uint32_t bank) {
    uint64_t src = (bank & 16u) ? hi : lo;
    return (uint32_t)(src >> ((bank & 15u) * 4)) & 0xFu;
}

__global__ __launch_bounds__(64)
void prep_sched(const int2* __restrict__ idx0,    // 16384 pairs, [0,256)
                const int*  __restrict__ nor0,    // 16384
                const int2* __restrict__ idx_mid, // 15*16384 pairs, [0,16384)
                const int*  __restrict__ nor_mid, // 15*16384
                uint32_t*   __restrict__ ws)      // 16*16384 descriptors
{
    __shared__ uint32_t desc_s[1024];

    const int l = blockIdx.x >> 4;   // layer 0..15
    const int w = blockIdx.x & 15;   // wave group 0..15
    const int t = threadIdx.x;       // 0..63

    const int2* idx = (l == 0) ? idx0 : idx_mid + (size_t)(l - 1) * N_GATES;
    const int*  nor = (l == 0) ? nor0 : nor_mid + (size_t)(l - 1) * N_GATES;

    // stage this (layer,wave-group)'s 1024 gate descs into LDS (coalesced).
    // wave-group w's gates: g = w*256 + q*4096 + i  (q 0..3, i = lane*4+k)
    for (int j = t; j < 1024; j += 64) {
        int q = j >> 8, i = j & 255;
        int g = w * 256 + q * 4096 + i;
        int2 ab = idx[g];
        desc_s[j] = (uint32_t)ab.x | ((uint32_t)ab.y << 14) | ((uint32_t)nor[g] << 28);
    }
    __syncthreads();

    if (t < 16) {
        const int q = t >> 2, k = t & 3;
        uint64_t cA0 = 0, cA1 = 0, cB0 = 0, cB1 = 0;   // packed 4-bit bank loads
        uint32_t* dst = ws + (size_t)l * N_GATES;
        #pragma unroll 4
        for (int lane = 0; lane < 64; ++lane) {
            uint32_t d = desc_s[q * 256 + lane * 4 + k];
            uint32_t a = d & 0x3FFFu, b = (d >> 14) & 0x3FFFu, n = d >> 28;
            uint32_t ba = (a >> 1) & 31u, bb = (b >> 1) & 31u;
            uint32_t laa = nib_get(cA0, cA1, ba), lbb = nib_get(cB0, cB1, bb);
            uint32_t lab = nib_get(cA0, cA1, bb), lba = nib_get(cB0, cB1, ba);
            uint32_t c0 = laa > lbb ? laa : lbb;       // keep order
            uint32_t c1 = lab > lba ? lab : lba;       // swapped
            bool sw = c1 < c0;
            uint32_t s0  = sw ? b : a,    s1  = sw ? a : b;
            uint32_t bs0 = sw ? bb : ba,  bs1 = sw ? ba : bb;
            uint32_t l0  = sw ? lab : laa, l1 = sw ? lba : lbb;
            if (l0 < 15u) { uint64_t one = 1ull << ((bs0 & 15u) * 4); if (bs0 & 16u) cA1 += one; else cA0 += one; }
            if (l1 < 15u) { uint64_t one = 1ull << ((bs1 & 15u) * 4); if (bs1 & 16u) cB1 += one; else cB0 += one; }
            uint32_t Q = (uint32_t)(w * 64 + lane + q * 1024);
            dst[Q * 4 + k] = (s0 << 1) | (n << 15) | (s1 << 17);
        }
    }
}

// ---------------------------------------------------------------------------
// Main kernel (scheduled descriptors). One WG owns 16 bit-columns (u16
// words); full layer slice 32KB, double-buffered; 17 layers in-workgroup.
// ---------------------------------------------------------------------------
__global__ __launch_bounds__(BLOCK, 2)
void nand_graph_sched(const uint32_t* __restrict__ input_bits, // 256*4096 int 0/1
                      const uint32_t* __restrict__ ws_desc,    // 16*16384 packed descs
                      const int2*     __restrict__ idx_out,    // 256 pairs
                      const uint32_t* __restrict__ nor_out,    // 256 flags
                      int*            __restrict__ out)        // 256*4096 int 0/1
{
    extern __shared__ __align__(16) uint16_t lds16[];
    uint16_t* bufA = lds16;
    uint16_t* bufB = lds16 + N_GATES;
    uint16_t* wrd  = lds16 + 2 * N_GATES;   // 256 u16

    const int tid     = threadIdx.x;
    const int lane    = tid & 63;
    const int wave    = tid >> 6;
    const int colbase = blockIdx.x * WG_COLS;
    const uint4* dsc4 = reinterpret_cast<const uint4*>(ws_desc); // [l*4096 + q*1024 + tid]

    uint4 dsc[QPT];
    #pragma unroll
    for (int q = 0; q < QPT; ++q)            // layer-0 descriptors
        dsc[q] = dsc4[q * 1024 + tid];

    // ---- pack input_bits columns [colbase, colbase+16) into wrd[256] ----
    #pragma unroll
    for (int it = wave; it < NUM_IN / 4; it += BLOCK / 64) {
        int r = it * 4 + (lane >> 4);
        int c = lane & 15;
        uint32_t v = input_bits[r * W + colbase + c];
        unsigned long long m = __ballot(v != 0u);
        if ((lane & 15) == 0)
            wrd[r] = (uint16_t)(m >> ((lane >> 4) * 16));
    }
    __syncthreads();

    auto gate = [](const uint16_t* __restrict__ src, uint32_t d) -> uint32_t {
        uint32_t a2 = d & 0x7FFEu;
        uint32_t b2 = d >> 16;
        uint32_t va = *(const uint16_t*)((const char*)src + a2);
        uint32_t vb = *(const uint16_t*)((const char*)src + b2);
        return ~((d & 0x8000u) ? (va | vb) : (va & vb));
    };

    auto run_gates = [&](const uint16_t* __restrict__ src, uint16_t* __restrict__ dst) {
        #pragma unroll
        for (int q = 0; q < QPT; ++q) {
            int Q = tid + q * BLOCK;
            uint32_t r0 = gate(src, dsc[q].x);
            uint32_t r1 = gate(src, dsc[q].y);
            uint32_t r2 = gate(src, dsc[q].z);
            uint32_t r3 = gate(src, dsc[q].w);
            uint32_t lo = (r0 & 0xFFFFu) | (r1 << 16);
            uint32_t hi = (r2 & 0xFFFFu) | (r3 << 16);
            *reinterpret_cast<uint2*>(dst + 4 * Q) = make_uint2(lo, hi); // ds_write_b64, conflict-free
        }
    };

    // ---- layer 0 (reads wrd) ----
    run_gates(wrd, bufA);
    #pragma unroll
    for (int q = 0; q < QPT; ++q)            // prefetch mid-layer 0 descs
        dsc[q] = dsc4[1 * 4096 + q * 1024 + tid];
    __syncthreads();

    // ---- 15 mid layers, ping-pong, descriptor prefetch across barrier ----
    uint16_t* cur = bufA;
    uint16_t* nxt = bufB;
    for (int l = 1; l <= MID_LAYERS; ++l) {
        run_gates(cur, nxt);
        if (l + 1 <= MID_LAYERS) {
            #pragma unroll
            for (int q = 0; q < QPT; ++q)
                dsc[q] = dsc4[(l + 1) * 4096 + q * 1024 + tid];
        }
        __syncthreads();
        uint16_t* tp = cur; cur = nxt; nxt = tp;
    }

    // ---- output layer: 256 gates -> wrd ----
    if (tid < NUM_OUT) {
        int2 ix = idx_out[tid];
        uint32_t a = cur[ix.x];
        uint32_t b = cur[ix.y];
        wrd[tid] = (uint16_t)~(nor_out[tid] ? (a | b) : (a & b));
    }
    __syncthreads();

    // ---- unpack: 256 rows x 16 cols of int 0/1 ----
    for (int i = tid; i < NUM_OUT * WG_COLS; i += BLOCK) {
        int r = i >> 4, c = i & 15;
        out[r * W + colbase + c] = (int)((wrd[r] >> c) & 1u);
    }
}

// ---------------------------------------------------------------------------
// Fallback (R4 kernel, unscheduled) — used only if ws_size < 1MB.
// ---------------------------------------------------------------------------
__global__ __launch_bounds__(BLOCK, 2)
void nand_graph_kernel(const uint32_t* __restrict__ input_bits,
                       const int4*     __restrict__ idx0_4,
                       const int4*     __restrict__ idx_mid_4,
                       const int2*     __restrict__ idx_out,
                       const int4*     __restrict__ nor0_4,
                       const int4*     __restrict__ nor_mid_4,
                       const uint32_t* __restrict__ nor_out,
                       int*            __restrict__ out)
{
    extern __shared__ __align__(16) uint16_t lds16[];
    uint16_t* bufA = lds16;
    uint16_t* bufB = lds16 + N_GATES;
    uint16_t* wrd  = lds16 + 2 * N_GATES;

    const int tid     = threadIdx.x;
    const int lane    = tid & 63;
    const int wave    = tid >> 6;
    const int colbase = blockIdx.x * WG_COLS;

    int4 ixA[QPT], ixB[QPT], nnq[QPT];
    #pragma unroll
    for (int q = 0; q < QPT; ++q) {
        int Q = tid + q * BLOCK;
        ixA[q] = idx0_4[2 * Q];
        ixB[q] = idx0_4[2 * Q + 1];
        nnq[q] = nor0_4[Q];
    }
    #pragma unroll
    for (int it = wave; it < NUM_IN / 4; it += BLOCK / 64) {
        int r = it * 4 + (lane >> 4);
        int c = lane & 15;
        uint32_t v = input_bits[r * W + colbase + c];
        unsigned long long m = __ballot(v != 0u);
        if ((lane & 15) == 0)
            wrd[r] = (uint16_t)(m >> ((lane >> 4) * 16));
    }
    __syncthreads();

    auto run_gates = [&](const uint16_t* __restrict__ src, uint16_t* __restrict__ dst) {
        #pragma unroll
        for (int q = 0; q < QPT; ++q) {
            int Q = tid + q * BLOCK;
            uint32_t a0 = src[ixA[q].x], b0 = src[ixA[q].y];
            uint32_t a1 = src[ixA[q].z], b1 = src[ixA[q].w];
            uint32_t a2 = src[ixB[q].x], b2 = src[ixB[q].y];
            uint32_t a3 = src[ixB[q].z], b3 = src[ixB[q].w];
            uint32_t r0 = ~(nnq[q].x ? (a0 | b0) : (a0 & b0));
            uint32_t r1 = ~(nnq[q].y ? (a1 | b1) : (a1 & b1));
            uint32_t r2 = ~(nnq[q].z ? (a2 | b2) : (a2 & b2));
            uint32_t r3 = ~(nnq[q].w ? (a3 | b3) : (a3 & b3));
            uint32_t lo = (r0 & 0xFFFFu) | (r1 << 16);
            uint32_t hi = (r2 & 0xFFFFu) | (r3 << 16);
            *reinterpret_cast<uint2*>(dst + 4 * Q) = make_uint2(lo, hi);
        }
    };

    run_gates(wrd, bufA);
    {
        #pragma unroll
        for (int q = 0; q < QPT; ++q) {
            int Q = tid + q * BLOCK;
            ixA[q] = idx_mid_4[2 * Q];
            ixB[q] = idx_mid_4[2 * Q + 1];
            nnq[q] = nor_mid_4[Q];
        }
    }
    __syncthreads();

    uint16_t* cur = bufA;
    uint16_t* nxt = bufB;
    for (int l = 0; l < MID_LAYERS; ++l) {
        run_gates(cur, nxt);
        if (l + 1 < MID_LAYERS) {
            const int4* i4 = idx_mid_4 + (size_t)(l + 1) * (N_GATES / 2);
            const int4* n4 = nor_mid_4 + (size_t)(l + 1) * (N_GATES / 4);
            #pragma unroll
            for (int q = 0; q < QPT; ++q) {
                int Q = tid + q * BLOCK;
                ixA[q] = i4[2 * Q];
                ixB[q] = i4[2 * Q + 1];
                nnq[q] = n4[Q];
            }
        }
        __syncthreads();
        uint16_t* tp = cur; cur = nxt; nxt = tp;
    }

    if (tid < NUM_OUT) {
        int2 ix = idx_out[tid];
        uint32_t a = cur[ix.x];
        uint32_t b = cur[ix.y];
        wrd[tid] = (uint16_t)~(nor_out[tid] ? (a | b) : (a & b));
    }
    __syncthreads();
    for (int i = tid; i < NUM_OUT * WG_COLS; i += BLOCK) {
        int r = i >> 4, c = i & 15;
        out[r * W + colbase + c] = (int)((wrd[r] >> c) & 1u);
    }
}

extern "C" void kernel_launch(void* const* d_in, const int* in_sizes, int n_in,
                              void* d_out, int out_size, void* d_ws, size_t ws_size,
                              hipStream_t stream) {
    const uint32_t* input_bits = (const uint32_t*)d_in[0];
    const int2*     idx0       = (const int2*)d_in[1];
    const int2*     idx_mid    = (const int2*)d_in[2];
    const int2*     idx_out    = (const int2*)d_in[3];
    const int*      nor0       = (const int*)d_in[4];
    const int*      nor_mid    = (const int*)d_in[5];
    const uint32_t* nor_out    = (const uint32_t*)d_in[6];
    int*            out        = (int*)d_out;

    const size_t lds_bytes = (size_t)(2 * N_GATES + 256) * sizeof(uint16_t); // 66048 B
    const size_t desc_bytes = (size_t)LAYERS_TOT * N_GATES * sizeof(uint32_t); // 1 MB

    if (ws_size >= desc_bytes) {
        uint32_t* ws = (uint32_t*)d_ws;
        prep_sched<<<dim3(256), dim3(64), 0, stream>>>(idx0, nor0, idx_mid, nor_mid, ws);
        hipFuncSetAttribute(reinterpret_cast<const void*>(nand_graph_sched),
                            hipFuncAttributeMaxDynamicSharedMemorySize, (int)lds_bytes);
        nand_graph_sched<<<dim3(NUM_WG), dim3(BLOCK), lds_bytes, stream>>>(
            input_bits, ws, idx_out, nor_out, out);
    } else {
        hipFuncSetAttribute(reinterpret_cast<const void*>(nand_graph_kernel),
                            hipFuncAttributeMaxDynamicSharedMemorySize, (int)lds_bytes);
        nand_graph_kernel<<<dim3(NUM_WG), dim3(BLOCK), lds_bytes, stream>>>(
            input_bits, (const int4*)idx0, (const int4*)idx_mid, idx_out,
            (const int4*)nor0, (const int4*)nor_mid, nor_out, out);
    }
}

// Round 7
// 49.503 us; speedup vs baseline: 1.1294x; 1.1294x over previous
//
#include <hip/hip_runtime.h>
#include <stdint.h>

#define N_GATES    16384
#define NUM_IN     256
#define NUM_OUT    256
#define MID_LAYERS 15
#define W          4096
#define BLOCK      1024
#define WG_COLS    16              // bit-columns per workgroup (uint16 words)
#define NUM_WG     (W / WG_COLS)   // 256 -> one WG per CU
#define OPT        2               // octs (of 8 gates) per thread: 2*1024*8 = 16384

// One workgroup owns 16 bit-columns as uint16 words. Full layer slice =
// 16384 x 2B = 32KB, double-buffered (64KB) + 512B packed I/O words.
// All 17 layers run in-workgroup, one __syncthreads() per layer.
//
// MLP-maximizing inner loop: each thread issues ALL 32 gather ds_read_u16
// into registers (static indices -> no scratch) before combining, so each
// wave keeps 32 LDS ops outstanding (16 waves/CU -> deep LDS queue), then
// writes 8 packed gates with one ds_write_b128 per oct (32 write instrs
// per CU-layer). Descriptors for layer l+1 are fetched into registers
// before the barrier ending layer l, hiding L2 latency under the gathers.
__global__ __launch_bounds__(BLOCK, 4)
void nand_graph_kernel(const uint32_t* __restrict__ input_bits, // 256*4096 int 0/1
                       const int4*     __restrict__ idx0_4,     // layer0: 8192 int4 (2 gates each)
                       const int4*     __restrict__ idx_mid_4,  // 15*8192 int4
                       const int2*     __restrict__ idx_out,    // 256 pairs
                       const int4*     __restrict__ nor0_4,     // layer0: 4096 int4 (4 gates each)
                       const int4*     __restrict__ nor_mid_4,  // 15*4096 int4
                       const uint32_t* __restrict__ nor_out,    // 256 flags
                       int*            __restrict__ out)        // 256*4096 int 0/1
{
    extern __shared__ __align__(16) uint16_t lds16[];
    uint16_t* bufA = lds16;                 // 16384 u16
    uint16_t* bufB = lds16 + N_GATES;       // 16384 u16
    uint16_t* wrd  = lds16 + 2 * N_GATES;   // 256 u16 (input pack / output pack)

    const int tid     = threadIdx.x;        // 0..1023
    const int lane    = tid & 63;
    const int wave    = tid >> 6;           // 0..15
    const int colbase = blockIdx.x * WG_COLS;

    // Per-thread descriptors for the layer about to run.
    // Oct j covers gates 8*o..8*o+7 with o = tid + j*1024.
    // ix[j][u] = idx int4 for gates (8o+2u, 8o+2u+1); nn[j][u>>1] holds nor.
    int4 ix[OPT][4];
    int4 nn[OPT][2];

    auto load_desc = [&](const int4* __restrict__ i4, const int4* __restrict__ n4) {
        #pragma unroll
        for (int j = 0; j < OPT; ++j) {
            int o = tid + j * BLOCK;
            #pragma unroll
            for (int u = 0; u < 4; ++u) ix[j][u] = i4[4 * o + u];
            #pragma unroll
            for (int u = 0; u < 2; ++u) nn[j][u] = n4[2 * o + u];
        }
    };

    load_desc(idx0_4, nor0_4);   // layer-0 descriptors (hide under input pack)

    // ---- pack input_bits columns [colbase, colbase+16) into wrd[256] ----
    #pragma unroll
    for (int it = wave; it < NUM_IN / 4; it += BLOCK / 64) {
        int r = it * 4 + (lane >> 4);
        int c = lane & 15;
        uint32_t v = input_bits[r * W + colbase + c];
        unsigned long long m = __ballot(v != 0u);
        if ((lane & 15) == 0)
            wrd[r] = (uint16_t)(m >> ((lane >> 4) * 16));
    }
    __syncthreads();

    auto run_gates = [&](const uint16_t* __restrict__ src, uint16_t* __restrict__ dst) {
        // phase 1: issue all 32 gather reads into registers (static indices)
        uint32_t v[OPT][16];
        #pragma unroll
        for (int j = 0; j < OPT; ++j) {
            #pragma unroll
            for (int u = 0; u < 4; ++u) {
                v[j][4 * u + 0] = src[ix[j][u].x];
                v[j][4 * u + 1] = src[ix[j][u].y];
                v[j][4 * u + 2] = src[ix[j][u].z];
                v[j][4 * u + 3] = src[ix[j][u].w];
            }
        }
        // phase 2: combine and write 8 gates per oct with one ds_write_b128
        #pragma unroll
        for (int j = 0; j < OPT; ++j) {
            int o = tid + j * BLOCK;
            uint32_t w[4];
            #pragma unroll
            for (int u = 0; u < 4; ++u) {
                int nlo = (u & 1) ? nn[j][u >> 1].z : nn[j][u >> 1].x;
                int nhi = (u & 1) ? nn[j][u >> 1].w : nn[j][u >> 1].y;
                uint32_t a0 = v[j][4 * u + 0], b0 = v[j][4 * u + 1];
                uint32_t a1 = v[j][4 * u + 2], b1 = v[j][4 * u + 3];
                uint32_t r0 = ~(nlo ? (a0 | b0) : (a0 & b0));
                uint32_t r1 = ~(nhi ? (a1 | b1) : (a1 & b1));
                w[u] = (r0 & 0xFFFFu) | (r1 << 16);
            }
            *reinterpret_cast<uint4*>(dst + 8 * o) = make_uint4(w[0], w[1], w[2], w[3]);
        }
    };

    // ---- layer 0 (reads wrd) ----
    run_gates(wrd, bufA);
    load_desc(idx_mid_4, nor_mid_4);     // prefetch mid-layer 0 descriptors
    __syncthreads();

    // ---- 15 mid layers, ping-pong, descriptor prefetch across barrier ----
    uint16_t* cur = bufA;
    uint16_t* nxt = bufB;
    for (int m = 0; m < MID_LAYERS; ++m) {
        run_gates(cur, nxt);
        if (m + 1 < MID_LAYERS)
            load_desc(idx_mid_4 + (size_t)(m + 1) * (N_GATES / 2),
                      nor_mid_4 + (size_t)(m + 1) * (N_GATES / 4));
        __syncthreads();
        uint16_t* tp = cur; cur = nxt; nxt = tp;
    }

    // ---- output layer: 256 gates -> wrd ----
    if (tid < NUM_OUT) {
        int2 ixo = idx_out[tid];
        uint32_t a = cur[ixo.x];
        uint32_t b = cur[ixo.y];
        wrd[tid] = (uint16_t)~(nor_out[tid] ? (a | b) : (a & b));
    }
    __syncthreads();

    // ---- unpack: 256 rows x 16 cols of int 0/1 ----
    for (int i = tid; i < NUM_OUT * WG_COLS; i += BLOCK) {
        int r = i >> 4, c = i & 15;
        out[r * W + colbase + c] = (int)((wrd[r] >> c) & 1u);
    }
}

extern "C" void kernel_launch(void* const* d_in, const int* in_sizes, int n_in,
                              void* d_out, int out_size, void* d_ws, size_t ws_size,
                              hipStream_t stream) {
    const uint32_t* input_bits = (const uint32_t*)d_in[0];
    const int4*     idx0_4     = (const int4*)d_in[1];
    const int4*     idx_mid_4  = (const int4*)d_in[2];
    const int2*     idx_out    = (const int2*)d_in[3];
    const int4*     nor0_4     = (const int4*)d_in[4];
    const int4*     nor_mid_4  = (const int4*)d_in[5];
    const uint32_t* nor_out    = (const uint32_t*)d_in[6];
    int*            out        = (int*)d_out;

    const size_t lds_bytes = (size_t)(2 * N_GATES + 256) * sizeof(uint16_t); // 66048 B

    hipFuncSetAttribute(reinterpret_cast<const void*>(nand_graph_kernel),
                        hipFuncAttributeMaxDynamicSharedMemorySize, (int)lds_bytes);

    nand_graph_kernel<<<dim3(NUM_WG), dim3(BLOCK), lds_bytes, stream>>>(
        input_bits, idx0_4, idx_mid_4, idx_out, nor0_4, nor_mid_4, nor_out, out);
}

// Round 8
// 49.291 us; speedup vs baseline: 1.1343x; 1.0043x over previous
//
#include <hip/hip_runtime.h>
#include <stdint.h>

#define N_GATES    16384
#define NUM_IN     256
#define NUM_OUT    256
#define MID_LAYERS 15
#define W          4096
#define BLOCK      1024
#define WG_COLS    16              // bit-columns per workgroup (uint16 words)
#define NUM_WG     (W / WG_COLS)   // 256 -> one WG per CU
#define OPT        2               // octs (of 8 gates) per thread: 2*1024*8 = 16384

// One workgroup owns 16 bit-columns as uint16 words. Full layer slice =
// 16384 x 2B = 32KB, double-buffered (64KB) + 512B packed I/O words.
// All 17 layers run in-workgroup, one __syncthreads() per layer.
//
// Regime (established R2-R7): DS-pipe INSTRUCTION-ISSUE bound, ~5.8-6.3 cyc
// per wave-LDS-instruction sustained, plus ~4.9 cyc/read inherent bank
// conflict for random gathers. Per-CU per-layer floor: 512 gather reads
// (hard floor: 2*16384/64, u16@256WG is the unique all-CUs-busy config)
// + 32 oct-packed b128 writes. Combine stays interleaved pair-by-pair
// (R7 showed batching reads regresses); stores are oct-accumulated.
__global__ __launch_bounds__(BLOCK, 4)
void nand_graph_kernel(const uint32_t* __restrict__ input_bits, // 256*4096 int 0/1
                       const int4*     __restrict__ idx0_4,     // layer0: 8192 int4 (2 gates each)
                       const int4*     __restrict__ idx_mid_4,  // 15*8192 int4
                       const int2*     __restrict__ idx_out,    // 256 pairs
                       const int4*     __restrict__ nor0_4,     // layer0: 4096 int4 (4 gates each)
                       const int4*     __restrict__ nor_mid_4,  // 15*4096 int4
                       const uint32_t* __restrict__ nor_out,    // 256 flags
                       int*            __restrict__ out)        // 256*4096 int 0/1
{
    extern __shared__ __align__(16) uint16_t lds16[];
    uint16_t* bufA = lds16;                 // 16384 u16
    uint16_t* bufB = lds16 + N_GATES;       // 16384 u16
    uint16_t* wrd  = lds16 + 2 * N_GATES;   // 256 u16 (input pack / output pack)

    const int tid     = threadIdx.x;        // 0..1023
    const int lane    = tid & 63;
    const int wave    = tid >> 6;           // 0..15
    const int colbase = blockIdx.x * WG_COLS;

    // Per-thread descriptors. Oct j covers gates 8*o..8*o+7, o = tid+j*1024.
    // ix[j][u] = idx int4 for gates (8o+2u, 8o+2u+1); nn[j][u>>1] = nor flags.
    int4 ix[OPT][4];
    int4 nn[OPT][2];

    auto load_desc = [&](const int4* __restrict__ i4, const int4* __restrict__ n4) {
        #pragma unroll
        for (int j = 0; j < OPT; ++j) {
            int o = tid + j * BLOCK;
            #pragma unroll
            for (int u = 0; u < 4; ++u) ix[j][u] = i4[4 * o + u];
            #pragma unroll
            for (int u = 0; u < 2; ++u) nn[j][u] = n4[2 * o + u];
        }
    };

    load_desc(idx0_4, nor0_4);   // layer-0 descriptors (hide under input pack)

    // ---- pack input_bits columns [colbase, colbase+16) into wrd[256] ----
    #pragma unroll
    for (int it = wave; it < NUM_IN / 4; it += BLOCK / 64) {
        int r = it * 4 + (lane >> 4);
        int c = lane & 15;
        uint32_t v = input_bits[r * W + colbase + c];
        unsigned long long m = __ballot(v != 0u);
        if ((lane & 15) == 0)
            wrd[r] = (uint16_t)(m >> ((lane >> 4) * 16));
    }
    __syncthreads();

    // R4-style interleaved combine, oct-accumulated b128 store.
    auto run_gates = [&](const uint16_t* __restrict__ src, uint16_t* __restrict__ dst) {
        #pragma unroll
        for (int j = 0; j < OPT; ++j) {
            int o = tid + j * BLOCK;
            uint32_t w[4];
            #pragma unroll
            for (int u = 0; u < 4; ++u) {
                int4 q = ix[j][u];
                uint32_t a0 = src[q.x], b0 = src[q.y];
                uint32_t a1 = src[q.z], b1 = src[q.w];
                int nlo = (u & 1) ? nn[j][u >> 1].z : nn[j][u >> 1].x;
                int nhi = (u & 1) ? nn[j][u >> 1].w : nn[j][u >> 1].y;
                uint32_t r0 = ~(nlo ? (a0 | b0) : (a0 & b0));
                uint32_t r1 = ~(nhi ? (a1 | b1) : (a1 & b1));
                w[u] = (r0 & 0xFFFFu) | (r1 << 16);
            }
            *reinterpret_cast<uint4*>(dst + 8 * o) = make_uint4(w[0], w[1], w[2], w[3]);
        }
    };

    // ---- layer 0 (reads wrd) ----
    run_gates(wrd, bufA);
    load_desc(idx_mid_4, nor_mid_4);     // prefetch mid-layer 0 descriptors
    __syncthreads();

    // ---- 15 mid layers, ping-pong, descriptor prefetch across barrier ----
    uint16_t* cur = bufA;
    uint16_t* nxt = bufB;
    for (int m = 0; m < MID_LAYERS; ++m) {
        run_gates(cur, nxt);
        if (m + 1 < MID_LAYERS)
            load_desc(idx_mid_4 + (size_t)(m + 1) * (N_GATES / 2),
                      nor_mid_4 + (size_t)(m + 1) * (N_GATES / 4));
        __syncthreads();
        uint16_t* tp = cur; cur = nxt; nxt = tp;
    }

    // ---- output layer: 256 gates -> wrd ----
    if (tid < NUM_OUT) {
        int2 ixo = idx_out[tid];
        uint32_t a = cur[ixo.x];
        uint32_t b = cur[ixo.y];
        wrd[tid] = (uint16_t)~(nor_out[tid] ? (a | b) : (a & b));
    }
    __syncthreads();

    // ---- unpack: 256 rows x 16 cols of int 0/1 ----
    for (int i = tid; i < NUM_OUT * WG_COLS; i += BLOCK) {
        int r = i >> 4, c = i & 15;
        out[r * W + colbase + c] = (int)((wrd[r] >> c) & 1u);
    }
}

extern "C" void kernel_launch(void* const* d_in, const int* in_sizes, int n_in,
                              void* d_out, int out_size, void* d_ws, size_t ws_size,
                              hipStream_t stream) {
    const uint32_t* input_bits = (const uint32_t*)d_in[0];
    const int4*     idx0_4     = (const int4*)d_in[1];
    const int4*     idx_mid_4  = (const int4*)d_in[2];
    const int2*     idx_out    = (const int2*)d_in[3];
    const int4*     nor0_4     = (const int4*)d_in[4];
    const int4*     nor_mid_4  = (const int4*)d_in[5];
    const uint32_t* nor_out    = (const uint32_t*)d_in[6];
    int*            out        = (int*)d_out;

    const size_t lds_bytes = (size_t)(2 * N_GATES + 256) * sizeof(uint16_t); // 66048 B

    hipFuncSetAttribute(reinterpret_cast<const void*>(nand_graph_kernel),
                        hipFuncAttributeMaxDynamicSharedMemorySize, (int)lds_bytes);

    nand_graph_kernel<<<dim3(NUM_WG), dim3(BLOCK), lds_bytes, stream>>>(
        input_bits, idx0_4, idx_mid_4, idx_out, nor0_4, nor_mid_4, nor_out, out);
}

// Round 9
// 43.916 us; speedup vs baseline: 1.2731x; 1.1224x over previous
//
#include <hip/hip_runtime.h>
#include <stdint.h>

#define N_GATES    16384
#define NUM_IN     256
#define NUM_OUT    256
#define MID_LAYERS 15
#define W          4096
#define BLOCK      1024
#define WG_COLS    16              // bit-columns per workgroup (uint16 words)
#define NUM_WG     (W / WG_COLS)   // 256 -> one WG per CU on all 256 CUs
#define QPT        (N_GATES / (4 * BLOCK))  // 4 quads (of 4 gates) per thread

// One workgroup owns 16 bit-columns as uint16 words. Full layer slice =
// 16384 x 2B = 32KB, double-buffered (64KB) + 512B packed I/O words.
// All 17 layers run in-workgroup, one __syncthreads() per layer.
//
// Regime (established R2-R8): DS-pipe instruction-issue bound. Per-CU
// per-layer: 512 random-gather ds_read_u16 x ~5.8 cyc issue + ~2540 cyc
// inherent conflict (random 64 lanes over 32 banks, E[max]~5, m136 N/2.8)
// + 128 paired ds_write_b64 + barrier ~= 6380 cyc; x16 layers ~= 42.5us.
// Measured alternatives that regress: u32 words/128WG (R2/R3), MLP read
// batching (R7), oct b128 stores (R8), runtime two-choice scheduling prep
// (R5/R6: main -3.6us but prep+launch +12us). This structure is the
// measured local optimum; descriptor loads for layer l+1 issue BEFORE the
// barrier ending layer l so L2 latency hides under the gathers.
__global__ __launch_bounds__(BLOCK, 2)
void nand_graph_kernel(const uint32_t* __restrict__ input_bits, // 256*4096 int 0/1
                       const int4*     __restrict__ idx0_4,     // 16384 pairs as 8192 int4
                       const int4*     __restrict__ idx_mid_4,  // 15*8192 int4
                       const int2*     __restrict__ idx_out,    // 256 pairs
                       const int4*     __restrict__ nor0_4,     // 16384 flags as 4096 int4
                       const int4*     __restrict__ nor_mid_4,  // 15*4096 int4
                       const uint32_t* __restrict__ nor_out,    // 256 flags
                       int*            __restrict__ out)        // 256*4096 int 0/1
{
    extern __shared__ __align__(16) uint16_t lds16[];
    uint16_t* bufA = lds16;                 // 16384 u16
    uint16_t* bufB = lds16 + N_GATES;       // 16384 u16
    uint16_t* wrd  = lds16 + 2 * N_GATES;   // 256 u16 (input pack / output pack)

    const int tid     = threadIdx.x;        // 0..1023
    const int lane    = tid & 63;
    const int wave    = tid >> 6;           // 0..15
    const int colbase = blockIdx.x * WG_COLS;

    int4 ixA[QPT], ixB[QPT], nnq[QPT];      // descriptors for the layer about to run

    // ---- issue layer-0 descriptor loads early (hide under input pack) ----
    #pragma unroll
    for (int q = 0; q < QPT; ++q) {
        int Q = tid + q * BLOCK;            // quad index; gates 4Q..4Q+3
        ixA[q] = idx0_4[2 * Q];
        ixB[q] = idx0_4[2 * Q + 1];
        nnq[q] = nor0_4[Q];
    }

    // ---- pack input_bits columns [colbase, colbase+16) into wrd[256] ----
    #pragma unroll
    for (int it = wave; it < NUM_IN / 4; it += BLOCK / 64) {
        int r = it * 4 + (lane >> 4);
        int c = lane & 15;
        uint32_t v = input_bits[r * W + colbase + c];
        unsigned long long m = __ballot(v != 0u);
        if ((lane & 15) == 0)
            wrd[r] = (uint16_t)(m >> ((lane >> 4) * 16));
    }
    __syncthreads();

    auto run_gates = [&](const uint16_t* __restrict__ src, uint16_t* __restrict__ dst) {
        #pragma unroll
        for (int q = 0; q < QPT; ++q) {
            int Q = tid + q * BLOCK;
            uint32_t a0 = src[ixA[q].x], b0 = src[ixA[q].y];
            uint32_t a1 = src[ixA[q].z], b1 = src[ixA[q].w];
            uint32_t a2 = src[ixB[q].x], b2 = src[ixB[q].y];
            uint32_t a3 = src[ixB[q].z], b3 = src[ixB[q].w];
            uint32_t r0 = ~(nnq[q].x ? (a0 | b0) : (a0 & b0));
            uint32_t r1 = ~(nnq[q].y ? (a1 | b1) : (a1 & b1));
            uint32_t r2 = ~(nnq[q].z ? (a2 | b2) : (a2 & b2));
            uint32_t r3 = ~(nnq[q].w ? (a3 | b3) : (a3 & b3));
            uint32_t lo = (r0 & 0xFFFFu) | (r1 << 16);
            uint32_t hi = (r2 & 0xFFFFu) | (r3 << 16);
            // 4 gates packed -> one conflict-free ds_write_b64 (8B lane stride)
            *reinterpret_cast<uint2*>(dst + 4 * Q) = make_uint2(lo, hi);
        }
    };

    // ---- layer 0: gates read the 256 packed input words ----
    run_gates(wrd, bufA);
    // prefetch mid-layer 0 descriptors before the barrier
    {
        #pragma unroll
        for (int q = 0; q < QPT; ++q) {
            int Q = tid + q * BLOCK;
            ixA[q] = idx_mid_4[2 * Q];
            ixB[q] = idx_mid_4[2 * Q + 1];
            nnq[q] = nor_mid_4[Q];
        }
    }
    __syncthreads();

    // ---- 15 mid layers, LDS ping-pong, descriptor prefetch across barrier ----
    uint16_t* cur = bufA;
    uint16_t* nxt = bufB;
    for (int l = 0; l < MID_LAYERS; ++l) {
        run_gates(cur, nxt);
        if (l + 1 < MID_LAYERS) {
            const int4* i4 = idx_mid_4 + (size_t)(l + 1) * (N_GATES / 2);
            const int4* n4 = nor_mid_4 + (size_t)(l + 1) * (N_GATES / 4);
            #pragma unroll
            for (int q = 0; q < QPT; ++q) {
                int Q = tid + q * BLOCK;
                ixA[q] = i4[2 * Q];
                ixB[q] = i4[2 * Q + 1];
                nnq[q] = n4[Q];
            }
        }
        __syncthreads();
        uint16_t* tp = cur; cur = nxt; nxt = tp;
    }

    // ---- output layer: 256 gates -> wrd[256] ----
    if (tid < NUM_OUT) {
        int2 ix = idx_out[tid];
        uint32_t a = cur[ix.x];
        uint32_t b = cur[ix.y];
        wrd[tid] = (uint16_t)~(nor_out[tid] ? (a | b) : (a & b));
    }
    __syncthreads();

    // ---- unpack: 256 rows x 16 columns of int 0/1 ----
    #pragma unroll
    for (int i = tid; i < NUM_OUT * WG_COLS; i += BLOCK) {
        int r = i >> 4, c = i & 15;
        out[r * W + colbase + c] = (int)((wrd[r] >> c) & 1u);
    }
}

extern "C" void kernel_launch(void* const* d_in, const int* in_sizes, int n_in,
                              void* d_out, int out_size, void* d_ws, size_t ws_size,
                              hipStream_t stream) {
    const uint32_t* input_bits = (const uint32_t*)d_in[0];
    const int4*     idx0_4     = (const int4*)d_in[1];
    const int4*     idx_mid_4  = (const int4*)d_in[2];
    const int2*     idx_out    = (const int2*)d_in[3];
    const int4*     nor0_4     = (const int4*)d_in[4];
    const int4*     nor_mid_4  = (const int4*)d_in[5];
    const uint32_t* nor_out    = (const uint32_t*)d_in[6];
    int*            out        = (int*)d_out;

    const size_t lds_bytes = (size_t)(2 * N_GATES + 256) * sizeof(uint16_t); // 66048 B

    hipFuncSetAttribute(reinterpret_cast<const void*>(nand_graph_kernel),
                        hipFuncAttributeMaxDynamicSharedMemorySize, (int)lds_bytes);

    nand_graph_kernel<<<dim3(NUM_WG), dim3(BLOCK), lds_bytes, stream>>>(
        input_bits, idx0_4, idx_mid_4, idx_out, nor0_4, nor_mid_4, nor_out, out);
}